// Round 6
// baseline (118.116 us; speedup 1.0000x reference)
//
#include <hip/hip_runtime.h>
#include <hip/hip_bf16.h>
#include <stdint.h>

typedef __attribute__((ext_vector_type(8))) short bf16x8;
typedef __attribute__((ext_vector_type(4))) float f32x4;

#define NB 8192

__device__ __forceinline__ unsigned pkbf(float x, float y) {
    __hip_bfloat162 h = __float22bfloat162_rn(make_float2(x, y));  // v_cvt_pk_bf16_f32 (RNE)
    unsigned r;
    __builtin_memcpy(&r, &h, 4);
    return r;
}

__device__ __forceinline__ uint4 pack8(float4 a, float4 b) {
    uint4 r;
    r.x = pkbf(a.x, a.y);
    r.y = pkbf(a.z, a.w);
    r.z = pkbf(b.x, b.y);
    r.w = pkbf(b.z, b.w);
    return r;
}

// ---------------------------------------------------------------------------
// prep: W[512][2048] fp32 -> bf16, fragment-linear layout for MFMA B-operand.
// Only k < 1024 ever used. Fragment (kb,cb), kb,cb in [0,32):
//   uint4 index = (kb*32 + cb)*64 + lane
//   element j (0..7) = W[cb*16 + (lane&15)][kb*32 + (lane>>4)*8 + j]
// ---------------------------------------------------------------------------
__global__ __launch_bounds__(256)
void prep_w_kernel(const float* __restrict__ W, uint4* __restrict__ Wt) {
    int t = blockIdx.x * 256 + threadIdx.x;   // 0..65535
    int lane = t & 63;
    int frag = t >> 6;                         // kb*32 + cb
    int kb = frag >> 5, cb = frag & 31;
    int o = cb * 16 + (lane & 15);
    int k = kb * 32 + ((lane >> 4) << 3);
    const float* src = W + (size_t)o * 2048 + k;
    float4 a = *(const float4*)src;
    float4 b = *(const float4*)(src + 4);
    Wt[t] = pack8(a, b);
}

// ---------------------------------------------------------------------------
// score kernel v6: 768 blocks x 256 threads (4 waves). node = bid%6,
// tile = bid/6 (BM=64, all nodes have 128 tiles). BN=512: wave w owns cols
// [w*128, +128) -> acc[4][8] (128 AGPR). launch_bounds(256,2) -> 256-reg
// budget, 2 blocks/CU co-resident: independent barrier domains, so one
// block's stage-barrier drain is covered by the other block's MFMAs
// (the round-5 failure was 1 block/CU: 8-wave barrier = whole-CU stall).
// LDS A tile: bf16 fragment-linear, frag f = ks*4+mf, chunk index f*64+l,
// double-buffered (16 KB). Writes/reads lane-linear -> 0 bank conflicts
// (verified by counters in rounds 2/5). fp32->bf16 cvt once at stage time.
// ---------------------------------------------------------------------------
__global__ __launch_bounds__(256, 2)
void score_kernel(const float* __restrict__ x0, const float* __restrict__ x1,
                  const float* __restrict__ x2, const float* __restrict__ x3,
                  const float* __restrict__ x4, const float* __restrict__ x5,
                  const float* __restrict__ bias, const float* __restrict__ hvec,
                  const uint4* __restrict__ Wt, float* __restrict__ scores) {
    __shared__ uint4 lA[2][512];      // 2 x 8 KB bf16 tiles
    __shared__ float red[4][64];

    int bid = blockIdx.x;
    int node = bid % 6;
    int tile = bid / 6;               // 0..127
    const float* xp; int dn;
    switch (node) {
        case 0: xp = x0; dn = 1024; break;
        case 1: xp = x1; dn = 512;  break;
        case 2: xp = x2; dn = 512;  break;
        case 3: xp = x3; dn = 512;  break;
        case 4: xp = x4; dn = 1024; break;
        default: xp = x5; dn = 512; break;
    }
    int m0 = tile * 64;
    int t = threadIdx.x;
    int l = t & 63;
    int w = t >> 6;

    int nst = dn >> 6;                // 16 or 8 BK=64 stages

    // staging: thread t fills chunk t (ks=0, mf=t>>6) and chunk t+256 (ks=1)
    int srow = (t >> 6) * 16 + (l & 15);
    const float* g1 = xp + (size_t)(m0 + srow) * dn + ((l >> 4) << 3);
    const float* g2 = g1 + 32;

    // prologue: stage tile 0
    {
        float4 a0 = *(const float4*)g1;
        float4 a1 = *(const float4*)(g1 + 4);
        float4 c0 = *(const float4*)g2;
        float4 c1 = *(const float4*)(g2 + 4);
        lA[0][t] = pack8(a0, a1);
        lA[0][t + 256] = pack8(c0, c1);
    }
    __syncthreads();

    f32x4 acc[4][8];
#pragma unroll
    for (int mf = 0; mf < 4; ++mf)
#pragma unroll
        for (int nf = 0; nf < 8; ++nf)
            acc[mf][nf] = (f32x4){0.f, 0.f, 0.f, 0.f};

    for (int s = 0; s < nst; ++s) {
        int cur = s & 1;
        // A prefetch for stage s+1 (issue early, consume after MFMAs - T14)
        float4 a0, a1, c0, c1;
        bool hn = (s + 1) < nst;
        if (hn) {
            const float* q = g1 + (s + 1) * 64;
            a0 = *(const float4*)q;
            a1 = *(const float4*)(q + 4);
            const float* q2 = g2 + (s + 1) * 64;
            c0 = *(const float4*)q2;
            c1 = *(const float4*)(q2 + 4);
        }
        // B fragments for both kblocks (L2-hot, fragment-linear)
        bf16x8 bfr[2][8];
#pragma unroll
        for (int ks = 0; ks < 2; ++ks) {
            int kb = (s << 1) + ks;
            const uint4* wp = Wt + (((kb << 5) + (w << 3)) << 6) + l;
#pragma unroll
            for (int nf = 0; nf < 8; ++nf) {
                uint4 u = wp[nf << 6];
                __builtin_memcpy(&bfr[ks][nf], &u, 16);
            }
        }
        // A fragments from LDS (lane-linear ds_read_b128) + MFMA
#pragma unroll
        for (int ks = 0; ks < 2; ++ks) {
#pragma unroll
            for (int mf = 0; mf < 4; ++mf) {
                uint4 u = lA[cur][((ks << 2) + mf) * 64 + l];
                bf16x8 afr;
                __builtin_memcpy(&afr, &u, 16);
#pragma unroll
                for (int nf = 0; nf < 8; ++nf)
                    acc[mf][nf] = __builtin_amdgcn_mfma_f32_16x16x32_bf16(
                        afr, bfr[ks][nf], acc[mf][nf], 0, 0, 0);
            }
        }
        // stage s+1 into the other buffer
        if (hn) {
            lA[cur ^ 1][t] = pack8(a0, a1);
            lA[cur ^ 1][t + 256] = pack8(c0, c1);
        }
        __syncthreads();
    }

    // epilogue: tanh, dot with h, reduce to per-row score
    float bv[8], hv[8];
#pragma unroll
    for (int nf = 0; nf < 8; ++nf) {
        int o = (w << 7) + (nf << 4) + (l & 15);
        bv[nf] = bias[o];
        hv[nf] = hvec[o];
    }
#pragma unroll
    for (int mf = 0; mf < 4; ++mf) {
        float sc[4] = {0.f, 0.f, 0.f, 0.f};
#pragma unroll
        for (int nf = 0; nf < 8; ++nf) {
#pragma unroll
            for (int r = 0; r < 4; ++r) {
                float xv = acc[mf][nf][r] + bv[nf];
                float th = 1.f - 2.f * __builtin_amdgcn_rcpf(1.f + __expf(2.f * xv));
                sc[r] = fmaf(hv[nf], th, sc[r]);
            }
        }
#pragma unroll
        for (int r = 0; r < 4; ++r) {
            float v = sc[r];
            v += __shfl_xor(v, 1);
            v += __shfl_xor(v, 2);
            v += __shfl_xor(v, 4);
            v += __shfl_xor(v, 8);
            if ((l & 15) == 0)
                red[w][(mf << 4) + ((l >> 4) << 2) + r] = v;
        }
    }
    __syncthreads();
    if (t < 64) {
        float ssum = red[0][t] + red[1][t] + red[2][t] + red[3][t];
        scores[node * NB + m0 + t] = ssum;
    }
}

// ---------------------------------------------------------------------------
// z kernel: one wave per batch. softmax over 6 scores, then
// z[0:512]=sum beta_n x_n ; z[512:1024]=b0*ls+b4*ds ; z[1024:2048]=0
// ---------------------------------------------------------------------------
__global__ __launch_bounds__(256)
void z_kernel(const float* __restrict__ x0, const float* __restrict__ x1,
              const float* __restrict__ x2, const float* __restrict__ x3,
              const float* __restrict__ x4, const float* __restrict__ x5,
              const float* __restrict__ scores, float* __restrict__ out) {
    int wv = threadIdx.x >> 6;
    int lane = threadIdx.x & 63;
    int b = (blockIdx.x << 2) + wv;

    float s0 = scores[b];
    float s1 = scores[NB + b];
    float s2 = scores[2 * NB + b];
    float s3 = scores[3 * NB + b];
    float s4 = scores[4 * NB + b];
    float s5 = scores[5 * NB + b];
    float m = fmaxf(fmaxf(fmaxf(s0, s1), fmaxf(s2, s3)), fmaxf(s4, s5));
    float e0 = __expf(s0 - m), e1 = __expf(s1 - m), e2 = __expf(s2 - m);
    float e3 = __expf(s3 - m), e4 = __expf(s4 - m), e5 = __expf(s5 - m);
    float inv = __builtin_amdgcn_rcpf(e0 + e1 + e2 + e3 + e4 + e5);
    float b0 = e0 * inv, b1 = e1 * inv, b2 = e2 * inv;
    float b3 = e3 * inv, b4 = e4 * inv, b5 = e5 * inv;

    const float* pls = x0 + (size_t)b * 1024;
    const float* pA  = x1 + (size_t)b * 512;
    const float* plm = x2 + (size_t)b * 512;
    const float* pAT = x3 + (size_t)b * 512;
    const float* pds = x4 + (size_t)b * 1024;
    const float* pdm = x5 + (size_t)b * 512;
    float* po = out + (size_t)b * 2048;

#pragma unroll
    for (int j = 0; j < 2; ++j) {
        int c = (j << 8) + (lane << 2);
        float4 vls = *(const float4*)(pls + c);
        float4 vA  = *(const float4*)(pA + c);
        float4 vlm = *(const float4*)(plm + c);
        float4 vAT = *(const float4*)(pAT + c);
        float4 vds = *(const float4*)(pds + c);
        float4 vdm = *(const float4*)(pdm + c);
        float4 r;
        r.x = b0*vls.x + b1*vA.x + b2*vlm.x + b3*vAT.x + b4*vds.x + b5*vdm.x;
        r.y = b0*vls.y + b1*vA.y + b2*vlm.y + b3*vAT.y + b4*vds.y + b5*vdm.y;
        r.z = b0*vls.z + b1*vA.z + b2*vlm.z + b3*vAT.z + b4*vds.z + b5*vdm.z;
        r.w = b0*vls.w + b1*vA.w + b2*vlm.w + b3*vAT.w + b4*vds.w + b5*vdm.w;
        *(float4*)(po + c) = r;
    }
#pragma unroll
    for (int j = 0; j < 2; ++j) {
        int c = 512 + (j << 8) + (lane << 2);
        float4 vls = *(const float4*)(pls + c);
        float4 vds = *(const float4*)(pds + c);
        float4 r;
        r.x = b0*vls.x + b4*vds.x;
        r.y = b0*vls.y + b4*vds.y;
        r.z = b0*vls.z + b4*vds.z;
        r.w = b0*vls.w + b4*vds.w;
        *(float4*)(po + c) = r;
    }
    float4 zz = make_float4(0.f, 0.f, 0.f, 0.f);
#pragma unroll
    for (int j = 0; j < 4; ++j) {
        int c = 1024 + (j << 8) + (lane << 2);
        *(float4*)(po + c) = zz;
    }
}

extern "C" void kernel_launch(void* const* d_in, const int* in_sizes, int n_in,
                              void* d_out, int out_size, void* d_ws, size_t ws_size,
                              hipStream_t stream) {
    const float* x0   = (const float*)d_in[0];  // ls  [8192,1024]
    const float* x1   = (const float*)d_in[1];  // A   [8192,512]
    const float* x2   = (const float*)d_in[2];  // lm  [8192,512]
    const float* x3   = (const float*)d_in[3];  // AT  [8192,512]
    const float* x4   = (const float*)d_in[4];  // ds  [8192,1024]
    const float* x5   = (const float*)d_in[5];  // dm  [8192,512]
    const float* W    = (const float*)d_in[6];  // [512,2048]
    const float* bias = (const float*)d_in[7];  // [512]
    const float* hvec = (const float*)d_in[8];  // [512,1]

    uint4* Wt = (uint4*)d_ws;                              // 1 MB
    float* scores = (float*)((char*)d_ws + (1u << 20));    // 6*8192*4 = 192 KB

    prep_w_kernel<<<256, 256, 0, stream>>>(W, Wt);
    score_kernel<<<768, 256, 0, stream>>>(x0, x1, x2, x3, x4, x5, bias, hvec, Wt, scores);
    z_kernel<<<2048, 256, 0, stream>>>(x0, x1, x2, x3, x4, x5, scores, (float*)d_out);
}